// Round 2
// baseline (211.994 us; speedup 1.0000x reference)
//
#include <hip/hip_runtime.h>

// Shapes (fixed): B=4, N=256, D_MODEL=256, D_EDGE=64, H=8, C=32
#define NBATCH 4
#define NN 256
#define DM 256
#define DEDGE 64
#define NHEAD 8
#define CDIM 32

// workspace layout (float offsets)
#define OQ  0
#define OK  262144
#define OV  524288
#define OS  786432      // skip = x@W_s + b_s
#define OWT 1048576     // WeT[hc][d] = W_e[d][hc], 16384 floats
// total ws need: 1064960 floats = 4.06 MB

static __device__ __forceinline__ float4 ld4(const float* p) {
    return *reinterpret_cast<const float4*>(p);
}

// ---------------------------------------------------------------------------
// Kernel 1: Q/K/V/skip projections (vector f32 GEMM, 16-row tiles) + W_e transpose
// grid = 257 blocks x 256 threads. blocks 0..255: (mat = bid>>6, tile = bid&63)
// block 256: transpose W_e into WeT.
// ---------------------------------------------------------------------------
__global__ __launch_bounds__(256) void fused_qkvs(
    const float* __restrict__ x,
    const float* __restrict__ Wq, const float* __restrict__ bq,
    const float* __restrict__ Wk, const float* __restrict__ bk,
    const float* __restrict__ Wv, const float* __restrict__ bv,
    const float* __restrict__ Wsk, const float* __restrict__ bsk,
    const float* __restrict__ We, float* __restrict__ ws)
{
    const int t = threadIdx.x;
    const int bid = blockIdx.x;

    if (bid == 256) {   // W_e (64x256) -> WeT[hc*64+d]
        #pragma unroll
        for (int k = 0; k < 64; ++k) {
            int o = k * 256 + t;                    // o = hc*64 + d
            ws[OWT + o] = We[(o & 63) * 256 + (o >> 6)];
        }
        return;
    }

    __shared__ float xs[16 * 256];                  // 16-row x tile, 16 KB

    const int tile = bid & 63;                      // 64 tiles of 16 rows
    const int mat  = bid >> 6;
    const float* W; const float* bb; float* out;
    if      (mat == 0) { W = Wq;  bb = bq;  out = ws + OQ; }
    else if (mat == 1) { W = Wk;  bb = bk;  out = ws + OK; }
    else if (mat == 2) { W = Wv;  bb = bv;  out = ws + OV; }
    else               { W = Wsk; bb = bsk; out = ws + OS; }

    const int r0 = tile * 16;
    {
        const float4* xsrc = reinterpret_cast<const float4*>(x + r0 * 256);
        float4* xd = reinterpret_cast<float4*>(xs);
        #pragma unroll
        for (int k = 0; k < 4; ++k) xd[t + k * 256] = xsrc[t + k * 256];
    }
    __syncthreads();

    const int c4 = (t & 63) * 4;                    // 64 lanes cover 256 cols (float4)
    const int rg = t >> 6;                          // 4 row-groups of 4 rows
    float acc[4][4] = {};

    #pragma unroll 4
    for (int d = 0; d < 256; ++d) {
        float4 wv = ld4(&W[d * 256 + c4]);          // coalesced 1KB/wave-group
        #pragma unroll
        for (int rr = 0; rr < 4; ++rr) {
            float xv = xs[(rg * 4 + rr) * 256 + d]; // LDS broadcast within wave
            acc[rr][0] += xv * wv.x; acc[rr][1] += xv * wv.y;
            acc[rr][2] += xv * wv.z; acc[rr][3] += xv * wv.w;
        }
    }

    float4 bv4 = ld4(&bb[c4]);
    #pragma unroll
    for (int rr = 0; rr < 4; ++rr) {
        float4 o;
        o.x = acc[rr][0] + bv4.x; o.y = acc[rr][1] + bv4.y;
        o.z = acc[rr][2] + bv4.z; o.w = acc[rr][3] + bv4.w;
        *reinterpret_cast<float4*>(&out[(r0 + rg * 4 + rr) * 256 + c4]) = o;
    }
}

// ---------------------------------------------------------------------------
// Kernel 2: fused edge-biased attention. One block per (b,i) row, thread t = source j.
// scores = (Q_i.K_j + edge_ij.P_i) * scale ; softmax over j ; out = alpha.(V+E) + skip
// E never materialized: P-trick (scores) and A-trick (output).
// Mask layout (byte-bool vs int32-bool) auto-detected from the first 4 KB.
// ---------------------------------------------------------------------------
__global__ __launch_bounds__(256) void fused_attn(
    const float* __restrict__ edge, const unsigned char* __restrict__ mask,
    const float* __restrict__ We, const float* __restrict__ ws,
    float* __restrict__ out)
{
    __shared__ float qs[256];       // Q row
    __shared__ float Ps[512];       // P[h][d]
    __shared__ float pt[8 * 260];   // scores then p, transposed [h][j]
    __shared__ float As[512];       // A[h][d]
    __shared__ float mx[8];
    __shared__ float sm[8];
    __shared__ int mflag;           // 1 = byte layout, 0 = int32 layout

    const float* Q  = ws + OQ;
    const float* K  = ws + OK;
    const float* V  = ws + OV;
    const float* SK = ws + OS;
    const float* WT = ws + OWT;

    const int t   = threadIdx.x;          // = source node j
    const int row = blockIdx.x;           // b*256 + i
    const int b   = row >> 8;
    const float* erow = edge + (size_t)row * (NN * DEDGE);

    if (t == 0) mflag = 0;
    __syncthreads();

    // --- mask layout detect: int32 0/1 values have zero bytes at off%4!=0 ---
    {
        int found = 0;
        #pragma unroll
        for (int k = 0; k < 16; ++k)
            if ((k & 3) != 0 && mask[t * 16 + k]) found = 1;
        if (found) mflag = 1;             // benign same-value race
    }

    qs[t] = Q[row * 256 + t];
    __syncthreads();

    const bool mk = mflag ? (mask[row * 256 + t] != 0)
                          : (reinterpret_cast<const int*>(mask)[row * 256 + t] != 0);

    // P[h][d] = sum_c q[h*32+c] * WeT[(h*32+c)*64 + d]   (coalesced WT reads)
    #pragma unroll
    for (int rep = 0; rep < 2; ++rep) {
        int idx = t + rep * 256;
        int h = idx >> 6, d = idx & 63;
        float a = 0.f;
        #pragma unroll
        for (int c = 0; c < 32; ++c) a += qs[h * 32 + c] * WT[(h * 32 + c) * 64 + d];
        Ps[idx] = a;
    }
    __syncthreads();

    // ---- scores for j = t ----
    float s[8];
    {
        const float* krow = K + ((b << 8) | t) * 256;
        #pragma unroll
        for (int h = 0; h < 8; ++h) {
            float a = 0.f;
            #pragma unroll
            for (int c = 0; c < 32; c += 4) {
                float4 kv = ld4(&krow[h * 32 + c]);
                float4 qv = ld4(&qs[h * 32 + c]);   // broadcast
                a += qv.x * kv.x + qv.y * kv.y + qv.z * kv.z + qv.w * kv.w;
            }
            s[h] = a;
        }
        // QE: edge row j dotted with P per head
        #pragma unroll
        for (int k = 0; k < 16; ++k) {
            float4 ev = ld4(&erow[t * 64 + k * 4]);
            #pragma unroll
            for (int h = 0; h < 8; ++h) {
                float4 pv = ld4(&Ps[h * 64 + k * 4]);  // broadcast
                s[h] += ev.x * pv.x + ev.y * pv.y + ev.z * pv.z + ev.w * pv.w;
            }
        }
        const float scale = 0.17677669529663687f;  // 1/sqrt(32)
        #pragma unroll
        for (int h = 0; h < 8; ++h) {
            s[h] *= scale;
            if (!mk) s[h] = -1e30f;
            pt[h * 260 + t] = s[h];
        }
    }
    __syncthreads();

    // ---- per-head max over j ----
    {
        int h = t >> 5, l = t & 31;
        float m = -1e30f;
        #pragma unroll
        for (int k = 0; k < 8; ++k) m = fmaxf(m, pt[h * 260 + l + k * 32]);
        #pragma unroll
        for (int off = 16; off; off >>= 1) m = fmaxf(m, __shfl_xor(m, off));
        if (l == 0) mx[h] = m;
    }
    __syncthreads();

    float p[8];
    #pragma unroll
    for (int h = 0; h < 8; ++h) {
        p[h] = mk ? __expf(s[h] - mx[h]) : 0.f;  // masked lanes exactly 0
        pt[h * 260 + t] = p[h];
    }
    __syncthreads();

    // ---- per-head sum over j ----
    {
        int h = t >> 5, l = t & 31;
        float a = 0.f;
        #pragma unroll
        for (int k = 0; k < 8; ++k) a += pt[h * 260 + l + k * 32];
        #pragma unroll
        for (int off = 16; off; off >>= 1) a += __shfl_xor(a, off);
        if (l == 0) sm[h] = a;                    // sum==0 => fully masked row
    }
    __syncthreads();

    // ---- out_V[h,c]: thread t = h*32+c ----
    float accV = 0.f;
    {
        int h = t >> 5;
        const float* vcol = V + (b << 8) * 256 + t;
        #pragma unroll 4
        for (int j4 = 0; j4 < 64; ++j4) {
            float4 pv = ld4(&pt[h * 260 + j4 * 4]);       // broadcast
            accV += pv.x * vcol[(j4 * 4 + 0) * 256];      // lanes coalesced over t
            accV += pv.y * vcol[(j4 * 4 + 1) * 256];
            accV += pv.z * vcol[(j4 * 4 + 2) * 256];
            accV += pv.w * vcol[(j4 * 4 + 3) * 256];
        }
    }

    // ---- A[h][d] = sum_j p[j,h]*edge[j,d] ; thread: d = t&63, h2 and h2+4 ----
    {
        int h2 = t >> 6, d = t & 63;
        float a0 = 0.f, a1 = 0.f;
        #pragma unroll 4
        for (int j4 = 0; j4 < 64; ++j4) {
            float4 p0 = ld4(&pt[h2 * 260 + j4 * 4]);
            float4 p1 = ld4(&pt[(h2 + 4) * 260 + j4 * 4]);
            float e0 = erow[(j4 * 4 + 0) * 64 + d];       // wave: 256B coalesced, L1-hot
            float e1 = erow[(j4 * 4 + 1) * 64 + d];
            float e2 = erow[(j4 * 4 + 2) * 64 + d];
            float e3 = erow[(j4 * 4 + 3) * 64 + d];
            a0 += p0.x * e0 + p0.y * e1 + p0.z * e2 + p0.w * e3;
            a1 += p1.x * e0 + p1.y * e1 + p1.z * e2 + p1.w * e3;
        }
        As[h2 * 64 + d] = a0;
        As[(h2 + 4) * 64 + d] = a1;
    }
    __syncthreads();

    // ---- out_E[h,c] = sum_d A[h,d]*W_e[d,hc], then normalize + skip ----
    {
        int h = t >> 5;
        float accE = 0.f;
        #pragma unroll
        for (int d4 = 0; d4 < 16; ++d4) {
            float4 av = ld4(&As[h * 64 + d4 * 4]);        // broadcast
            accE += av.x * We[(d4 * 4 + 0) * 256 + t];    // coalesced W_e rows
            accE += av.y * We[(d4 * 4 + 1) * 256 + t];
            accE += av.z * We[(d4 * 4 + 2) * 256 + t];
            accE += av.w * We[(d4 * 4 + 3) * 256 + t];
        }
        float denom = sm[h];
        float inv = denom > 0.f ? 1.f / denom : 0.f;      // nan_to_num for masked rows
        out[row * 256 + t] = (accV + accE) * inv + SK[row * 256 + t];
    }
}

// ---------------------------------------------------------------------------
extern "C" void kernel_launch(void* const* d_in, const int* in_sizes, int n_in,
                              void* d_out, int out_size, void* d_ws, size_t ws_size,
                              hipStream_t stream) {
    const float* x    = (const float*)d_in[0];
    const float* edge = (const float*)d_in[1];
    const unsigned char* mask = (const unsigned char*)d_in[2];  // layout auto-detected
    const float* Wq = (const float*)d_in[3];
    const float* bq = (const float*)d_in[4];
    const float* Wk = (const float*)d_in[5];
    const float* bk = (const float*)d_in[6];
    const float* Wv = (const float*)d_in[7];
    const float* bv = (const float*)d_in[8];
    const float* We = (const float*)d_in[9];
    const float* Wsk = (const float*)d_in[10];
    const float* bsk = (const float*)d_in[11];
    float* out = (float*)d_out;
    float* ws  = (float*)d_ws;

    fused_qkvs<<<257, 256, 0, stream>>>(x, Wq, bq, Wk, bk, Wv, bv, Wsk, bsk, We, ws);
    fused_attn<<<1024, 256, 0, stream>>>(edge, mask, We, ws, out);
}